// Round 11
// baseline (27.874 us; speedup 1.0000x reference)
//
#include <hip/hip_runtime.h>

// out[b,u] = tanh( exp( max_i x[b,i]*W[i,u] ) - 1 + bias[u] )
// exp monotonic -> max commutes -> max-times "GEMM" + transcendental epilogue.
//
// R11: maximize core:overhead instruction ratio. R4-R10 post-mortem: all
// k-split designs paid per-wave overhead (W preload, per-row s_loads, LDS
// combine) comparable to core compute -> issue floors of 13-19 us at 50-70%
// duty = the 26-31 us plateau. Fix: rows stream through ONE accumulator
// (no acc array -> rows/wave is VGPR-free), so 32 rows/wave gives core 1024
// vs overhead ~300 insts (3.4:1), floor ~9 us.
//   Block = 16 waves x 64 units (lane = unit), 32 rows, 16-way k-split.
//   Wave wv: W[wv*32..+31][u] as 16 v2f in VGPRs; x wave-uniform -> s_load,
//   consumed as the 64-bit SGPR operand of v_pk_mul_f32.
//   512 blocks = 2/CU, 32 waves/CU = 8/SIMD, one generation.

#define BATCH 2048
#define INDIM 512
#define UNITS 512

#define KC 32     // k-chunk per wave
#define RB 32     // rows per block
#define RGRP 16   // rows per combine group
#define NW 16     // waves per block (NW*KC == INDIM)

typedef float v2f __attribute__((ext_vector_type(2)));

__global__ __launch_bounds__(1024, 8) void maxexp_kernel(
    const float* __restrict__ x,     // [BATCH][INDIM]
    const float* __restrict__ W,     // [INDIM][UNITS]
    const float* __restrict__ bias,  // [UNITS]
    float* __restrict__ out)         // [BATCH][UNITS]
{
    __shared__ float part[RGRP][NW][64];   // 64 KB (2 blocks/CU = 128 <= 160)

    // bijective XCD swizzle: XCD (f&7) owns rows [xcd*256, +256), all u-tiles.
    const int f    = blockIdx.x;                    // 0..511
    const int band = (f & 7) * 8 + ((f >> 3) & 7);  // 0..63
    const int ut   = f >> 6;                        // 0..7

    const int lane = threadIdx.x & 63;
    const int wv   = __builtin_amdgcn_readfirstlane(threadIdx.x >> 6); // 0..15
    const int u    = ut * 64 + lane;     // unit (per-lane)
    const int k0   = wv * KC;            // k-chunk base (uniform)
    const int b0   = band * RB;          // first row (uniform)

    // ---- preload W chunk as 16 v2f pairs (32 VGPRs, coalesced loads) ----
    v2f wp[KC / 2];
    {
        const float* wb = W + (size_t)k0 * UNITS + u;
#pragma unroll
        for (int j = 0; j < KC / 2; ++j) {
            v2f t;
            t.x = wb[(size_t)(2 * j)     * UNITS];
            t.y = wb[(size_t)(2 * j + 1) * UNITS];
            wp[j] = t;
        }
    }
#pragma unroll
    for (int j = 0; j < KC / 2; ++j) asm("" : "+v"(wp[j]));

    const float bv = bias[u];
    const float* xb = x + (size_t)b0 * INDIM + k0;   // uniform base

#pragma unroll 1
    for (int g = 0; g < RB / RGRP; ++g) {   // 2 groups of 16 rows
        const float* xg = xb + (size_t)g * RGRP * INDIM;

        // ---- 16 rows stream through one accumulator pair ----
#pragma unroll
        for (int rr = 0; rr < RGRP; ++rr) {
            const v2f* xr = reinterpret_cast<const v2f*>(xg + (size_t)rr * INDIM);
            float m0 = -3.4e38f, m1 = -3.4e38f;   // two independent chains
#pragma unroll
            for (int j = 0; j < KC / 2; j += 2) {
                v2f p0, p1;
                // x pair from SGPRs (64-bit scalar operand), W pair from VGPRs
                asm("v_pk_mul_f32 %0, %1, %2" : "=v"(p0) : "s"(xr[j]),     "v"(wp[j]));
                asm("v_pk_mul_f32 %0, %1, %2" : "=v"(p1) : "s"(xr[j + 1]), "v"(wp[j + 1]));
                m0 = fmaxf(fmaxf(m0, p0.x), p0.y);   // -> v_max3_f32
                m1 = fmaxf(fmaxf(m1, p1.x), p1.y);
            }
            part[rr][wv][lane] = fmaxf(m0, m1);
        }

        __syncthreads();   // partials ready

        // ---- every wave combines one row: 16-way max, epilogue, store ----
        {
            float m = -3.4e38f;
#pragma unroll
            for (int j = 0; j < NW; j += 2)
                m = fmaxf(fmaxf(m, part[wv][j][lane]), part[wv][j + 1][lane]);
            const float pp = __expf(m) - 1.0f + bv;
            const float e  = __expf(2.0f * pp);
            out[(size_t)(b0 + g * RGRP + wv) * UNITS + u] = 1.0f - 2.0f / (e + 1.0f);
        }

        __syncthreads();   // part free for next group
    }
}

extern "C" void kernel_launch(void* const* d_in, const int* in_sizes, int n_in,
                              void* d_out, int out_size, void* d_ws, size_t ws_size,
                              hipStream_t stream) {
    const float* x    = (const float*)d_in[0];
    const float* W    = (const float*)d_in[1];
    const float* bias = (const float*)d_in[2];
    float* out = (float*)d_out;

    dim3 grid(512);    // 64 bands x 8 u-tiles; 2 blocks/CU, one generation
    dim3 block(1024);  // 16 waves
    maxexp_kernel<<<grid, block, 0, stream>>>(x, W, bias, out);
}